// Round 6
// baseline (5429.821 us; speedup 1.0000x reference)
//
#include <hip/hip_runtime.h>
#include <cstdint>
#include <cstddef>

#define T_S 64

typedef __attribute__((ext_vector_type(4))) float f32x4;
typedef __attribute__((ext_vector_type(8))) short bh8;

__device__ __forceinline__ unsigned short f2b(float f) {
  uint32_t x = __builtin_bit_cast(uint32_t, f);
  uint32_t r = (x + 0x7FFFu + ((x >> 16) & 1u)) >> 16;
  return (unsigned short)r;
}
__device__ __forceinline__ float b2f(unsigned short u) {
  uint32_t v = ((uint32_t)u) << 16;
  return __builtin_bit_cast(float, v);
}

// grid barrier: release add, RELAXED poll (no per-poll L2 invalidate!), one
// acquire fence on exit. Safe: 86KB dyn LDS forces 1 blk/CU -> 256 blocks
// co-resident. Occasional acquire load guards against a stuck relaxed poll.
__device__ __forceinline__ void gbar(int* bar, int target) {
  __syncthreads();
  if (threadIdx.x == 0) {
    __hip_atomic_fetch_add(bar, 1, __ATOMIC_RELEASE, __HIP_MEMORY_SCOPE_AGENT);
    int it = 0;
    while (__hip_atomic_load(bar, __ATOMIC_RELAXED, __HIP_MEMORY_SCOPE_AGENT) < target) {
      __builtin_amdgcn_s_sleep(2);
      if (((++it) & 1023) == 0)
        (void)__hip_atomic_load(bar, __ATOMIC_ACQUIRE, __HIP_MEMORY_SCOPE_AGENT);
    }
    __builtin_amdgcn_fence(__ATOMIC_ACQUIRE, "agent");
  }
  __syncthreads();
}

// ======================= prep =======================

__global__ void k_conv(const float* __restrict__ src, unsigned short* __restrict__ dst, int n4) {
  int i = blockIdx.x * blockDim.x + threadIdx.x;
  int stride = gridDim.x * blockDim.x;
  for (; i < n4; i += stride) {
    float4 v = ((const float4*)src)[i];
    ushort4 o; o.x = f2b(v.x); o.y = f2b(v.y); o.z = f2b(v.z); o.w = f2b(v.w);
    ((ushort4*)dst)[i] = o;
  }
}

// z=0 Wx -> WxT[4096][1024]; z=1/2 Wh/Wa -> PW[4096][2048] permuted:
// actual col = q*1024+cj*16+gl -> prow = cj*64 + q*16 + gl
__global__ __launch_bounds__(256) void k_tw3(
    const float* __restrict__ Wx, const float* __restrict__ Wh,
    const float* __restrict__ Wa,
    unsigned short* __restrict__ WxT, unsigned short* __restrict__ PW) {
  __shared__ float tile[64][65];
  int j0 = blockIdx.x * 64;
  int k0 = blockIdx.y * 64;
  int z = blockIdx.z;
  const float* src = (z == 0) ? Wx : (z == 1) ? Wh : Wa;
  for (int i = threadIdx.x; i < 4096; i += 256) {
    int r = i >> 6, c = i & 63;
    tile[r][c] = src[(size_t)(k0 + r) * 4096 + (j0 + c)];
  }
  __syncthreads();
  for (int i = threadIdx.x; i < 4096; i += 256) {
    int r = i >> 6, c = i & 63;
    int col = j0 + r;
    unsigned short v = f2b(tile[c][r]);
    if (z == 0) {
      WxT[(size_t)col * 1024 + (k0 + c)] = v;
    } else {
      int prow = ((col & 1023) >> 4) * 64 + (col >> 10) * 16 + (col & 15);
      PW[(size_t)prow * 2048 + (size_t)(z - 1) * 1024 + (k0 + c)] = v;
    }
  }
}

// xb2[(t*256+n)][k] = bf16(x[n][t][k])
__global__ __launch_bounds__(256) void k_conv_x2(
    const float* __restrict__ x, unsigned short* __restrict__ xb2) {
  int b = blockIdx.x, tid = threadIdx.x;
  #pragma unroll
  for (int rr = 0; rr < 4; ++rr) {
    int r = b * 4 + rr;
    int t = r >> 8, n = r & 255;
    const float4* src = (const float4*)(x + ((size_t)n * 64 + t) * 1024);
    float4 v = src[tid];
    ushort4 o; o.x = f2b(v.x); o.y = f2b(v.y); o.z = f2b(v.z); o.w = f2b(v.w);
    ((ushort4*)(xb2 + (size_t)r * 1024))[tid] = o;
  }
}

// h0 = c0 = mean(A over 16); h -> hx[n][0..1024) row stride 2048
__global__ __launch_bounds__(256) void k_init2(
    const float* __restrict__ A, unsigned short* __restrict__ hx,
    float* __restrict__ cst) {
  int idx = blockIdx.x * 256 + threadIdx.x;
  const float4* a4 = (const float4*)(A + (size_t)idx * 16);
  float s = 0.f;
  #pragma unroll
  for (int q = 0; q < 4; ++q) { float4 v = a4[q]; s += v.x + v.y + v.z + v.w; }
  s *= 0.0625f;
  cst[idx] = s;
  hx[(size_t)(idx >> 10) * 2048 + (idx & 1023)] = f2b(s);
}

// Tier-0 h0 (row stride 1024)
__global__ __launch_bounds__(256) void k_init1(
    const float* __restrict__ A, unsigned short* __restrict__ hb,
    float* __restrict__ cst) {
  int idx = blockIdx.x * 256 + threadIdx.x;
  const float4* a4 = (const float4*)(A + (size_t)idx * 16);
  float s = 0.f;
  #pragma unroll
  for (int q = 0; q < 4; ++q) { float4 v = a4[q]; s += v.x + v.y + v.z + v.w; }
  s *= 0.0625f;
  cst[idx] = s;
  hb[idx] = f2b(s);
}

// C = A[M][1024] @ Bt[4096][1024]^T. PERM=1: write xprojP layout
// row*4096 + cj*64 + q*16 + gl  (col = q*1024 + cj*16 + gl)
template <int PERM>
__global__ __launch_bounds__(512) void k_gemm_t(
    const unsigned short* __restrict__ Asrc,
    const unsigned short* __restrict__ Bt,
    unsigned short* __restrict__ C) {
  __shared__ __align__(16) unsigned short smem[36864];
  int tid = threadIdx.x;
  int bx = blockIdx.x, by = blockIdx.y;
  int lane = tid & 63, wave = tid >> 6;
  int wr = wave >> 1, wc = wave & 1;
  int srow = tid >> 3;
  int scol = (tid & 7) * 8;
  const unsigned short* arow0 = Asrc + ((size_t)(bx * 128 + srow)) * 1024 + scol;
  const unsigned short* arow1 = arow0 + (size_t)64 * 1024;
  const unsigned short* brow0 = Bt + ((size_t)(by * 128 + srow)) * 1024 + scol;
  const unsigned short* brow1 = brow0 + (size_t)64 * 1024;

  f32x4 acc[2][4];
  #pragma unroll
  for (int m = 0; m < 2; ++m)
    #pragma unroll
    for (int nn = 0; nn < 4; ++nn) acc[m][nn] = {0.f, 0.f, 0.f, 0.f};

  uint4 ra0, ra1, rb0, rb1;
  auto gload = [&](int kt) {
    int k0 = kt * 64;
    ra0 = *(const uint4*)(arow0 + k0);
    ra1 = *(const uint4*)(arow1 + k0);
    rb0 = *(const uint4*)(brow0 + k0);
    rb1 = *(const uint4*)(brow1 + k0);
  };
  int frow = lane & 15, fk = (lane >> 4) * 8;
  gload(0);
  int cur = 0;
  for (int kt = 0; kt < 16; ++kt) {
    unsigned short* As = smem + cur * 18432;
    unsigned short* Bs = As + 9216;
    *(uint4*)(As + srow * 72 + scol) = ra0;
    *(uint4*)(As + (srow + 64) * 72 + scol) = ra1;
    *(uint4*)(Bs + srow * 72 + scol) = rb0;
    *(uint4*)(Bs + (srow + 64) * 72 + scol) = rb1;
    __syncthreads();
    if (kt + 1 < 16) gload(kt + 1);
    #pragma unroll
    for (int kk = 0; kk < 2; ++kk) {
      bh8 af[2], bf[4];
      #pragma unroll
      for (int m = 0; m < 2; ++m)
        af[m] = *(const bh8*)(As + (wr * 32 + m * 16 + frow) * 72 + kk * 32 + fk);
      #pragma unroll
      for (int nn = 0; nn < 4; ++nn)
        bf[nn] = *(const bh8*)(Bs + (wc * 64 + nn * 16 + frow) * 72 + kk * 32 + fk);
      #pragma unroll
      for (int m = 0; m < 2; ++m)
        #pragma unroll
        for (int nn = 0; nn < 4; ++nn)
          acc[m][nn] = __builtin_amdgcn_mfma_f32_16x16x32_bf16(af[m], bf[nn], acc[m][nn], 0, 0, 0);
    }
    cur ^= 1;
  }
  int rbase = bx * 128 + wr * 32 + (lane >> 4) * 4;
  int cbase = by * 128 + wc * 64 + frow;
  #pragma unroll
  for (int m = 0; m < 2; ++m)
    #pragma unroll
    for (int nn = 0; nn < 4; ++nn)
      #pragma unroll
      for (int reg = 0; reg < 4; ++reg) {
        size_t row = rbase + m * 16 + reg;
        int c = cbase + nn * 16;
        size_t off = PERM ? ((size_t)row * 4096 + ((c >> 4) & 63) * 64 + (c >> 10) * 16 + (c & 15))
                          : ((size_t)row * 4096 + c);
        C[off] = f2b(acc[m][nn][reg]);
      }
}

// ======================= persistent step loop =======================
// 256 blocks x 512 thr, 86KB dyn LDS (1 blk/CU). LDS stride 132 shorts.
__global__ __launch_bounds__(512, 1) void k_steps(
    const unsigned short* __restrict__ Ab,     // [256][1024][16]
    const unsigned short* __restrict__ PW,     // [4096][2048] permuted Wh|Wa
    const unsigned short* __restrict__ xprojP, // [(t*256+n)][cj*64+q*16+gl]
    const float* __restrict__ bias,
    unsigned short* __restrict__ hxA,          // [256][2048] = [h|attn]
    unsigned short* __restrict__ hxB,
    const float* __restrict__ cst0,            // c0 init (read once)
    float* __restrict__ out,
    int* __restrict__ bar) {
  extern __shared__ __align__(16) unsigned short smem[];
  const int tid = threadIdx.x;
  const int bid = blockIdx.x;
  const int lane = tid & 63, wave = tid >> 6;
  const int wr = wave >> 1, wc = wave & 1;
  const int frow = lane & 15, fk = (lane >> 4) * 8;
  const int cj = (bid & 7) * 8 + ((bid >> 3) & 7);
  const int cn = bid >> 6;
  const int nbase = cn * 64, j0 = cj * 16;
  const int srow = tid >> 3;          // 0..63
  const int scol = (tid & 7) * 16;    // 0,16,..,112 shorts
  const unsigned short* bsrc = PW + ((size_t)(cj * 64 + srow)) * 2048 + scol;
  const int nA = bid;
  const int ST = 132;                 // LDS row stride (shorts): 264B = 2-bank step

  // persistent per-thread state: c and bias for the 2 (row,gl) pairs we own
  float creg0, creg1;
  float br0[4], br1[4];
  {
    int it0 = tid, it1 = 512 + tid;
    int row0 = it0 >> 4, gl0 = it0 & 15;
    int row1 = it1 >> 4, gl1 = it1 & 15;
    creg0 = cst0[(size_t)(nbase + row0) * 1024 + j0 + gl0];
    creg1 = cst0[(size_t)(nbase + row1) * 1024 + j0 + gl1];
    #pragma unroll
    for (int q = 0; q < 4; ++q) {
      br0[q] = bias[q * 1024 + j0 + gl0];
      br1[q] = bias[q * 1024 + j0 + gl1];
    }
  }

  int nb = 0;
  for (int t = 0; t < 64; ++t) {
    unsigned short* hxc = (t & 1) ? hxB : hxA;
    unsigned short* hxn = (t & 1) ? hxA : hxB;

    // ---------- Phase S+T: attention for n = bid ----------
    {
      uint hh = *(const uint*)(hxc + (size_t)nA * 2048 + tid * 2);
      float hv0 = b2f((unsigned short)(hh & 0xffff));
      float hv1 = b2f((unsigned short)(hh >> 16));
      const unsigned short* ap = Ab + (size_t)nA * 16384 + tid * 32;
      bh8 a0 = *(const bh8*)(ap);
      bh8 a1 = *(const bh8*)(ap + 8);
      bh8 a2 = *(const bh8*)(ap + 16);
      bh8 a3 = *(const bh8*)(ap + 24);
      float s[16];
      #pragma unroll
      for (int p = 0; p < 8; ++p) {
        s[p]     = hv0 * b2f((unsigned short)a0[p]) + hv1 * b2f((unsigned short)a2[p]);
        s[8 + p] = hv0 * b2f((unsigned short)a1[p]) + hv1 * b2f((unsigned short)a3[p]);
      }
      #pragma unroll
      for (int p = 0; p < 16; ++p) {
        float v = s[p];
        #pragma unroll
        for (int off = 32; off > 0; off >>= 1) v += __shfl_xor(v, off);
        s[p] = v;
      }
      float* red = (float*)smem;     // [8][16]
      float* scs = red + 128;        // [16]
      if (lane == 0) {
        #pragma unroll
        for (int p = 0; p < 16; ++p) red[wave * 16 + p] = s[p];
      }
      __syncthreads();
      if (tid < 16) {
        float v = 0.f;
        #pragma unroll
        for (int wv = 0; wv < 8; ++wv) v += red[wv * 16 + tid];
        scs[tid] = v * 0.03125f;
      }
      __syncthreads();
      float sc[16];
      #pragma unroll
      for (int p = 0; p < 16; ++p) sc[p] = scs[p];
      float m = sc[0];
      #pragma unroll
      for (int p = 1; p < 16; ++p) m = fmaxf(m, sc[p]);
      float w[16]; float sum = 0.f;
      #pragma unroll
      for (int p = 0; p < 16; ++p) { w[p] = __expf(sc[p] - m); sum += w[p]; }
      float inv = 1.0f / sum;
      float at0 = 0.f, at1 = 0.f;
      #pragma unroll
      for (int p = 0; p < 8; ++p) {
        at0 += w[p] * b2f((unsigned short)a0[p]) + w[8 + p] * b2f((unsigned short)a1[p]);
        at1 += w[p] * b2f((unsigned short)a2[p]) + w[8 + p] * b2f((unsigned short)a3[p]);
      }
      at0 *= inv; at1 *= inv;
      uint packed = (uint)f2b(at0) | ((uint)f2b(at1) << 16);
      *(uint*)(hxc + (size_t)nA * 2048 + 1024 + tid * 2) = packed;
    }
    nb += 1; gbar(bar, nb * 256);

    // ---------- Phase G: gates GEMM K=2048 + cell ----------
    {
      const unsigned short* asrc = hxc + (size_t)(nbase + srow) * 2048 + scol;
      // xproj slice for this block: issued now, consumed in epilogue
      uint4 xq = *(const uint4*)(xprojP + ((size_t)(t * 256 + nbase + srow)) * 4096
                                 + cj * 64 + (tid & 7) * 8);
      f32x4 acc0 = {0.f, 0.f, 0.f, 0.f};
      f32x4 acc1 = {0.f, 0.f, 0.f, 0.f};
      uint4 p0a0, p0a1, p0b0, p0b1, p1a0, p1a1, p1b0, p1b1;
      #define GLOAD(pa0, pa1, pb0, pb1, kt) { \
        const unsigned short* a_ = asrc + (kt) * 128; \
        const unsigned short* b_ = bsrc + (kt) * 128; \
        pa0 = *(const uint4*)(a_);      pa1 = *(const uint4*)(a_ + 8); \
        pb0 = *(const uint4*)(b_);      pb1 = *(const uint4*)(b_ + 8); }
      GLOAD(p0a0, p0a1, p0b0, p0b1, 0)
      GLOAD(p1a0, p1a1, p1b0, p1b1, 1)
      int cur = 0;
      for (int kt = 0; kt < 16; ++kt) {
        unsigned short* As = smem + cur * 16896;   // 64 x 132 shorts
        unsigned short* Bs = As + 8448;
        *(uint4*)(As + srow * ST + scol)     = p0a0;
        *(uint4*)(As + srow * ST + scol + 8) = p0a1;
        *(uint4*)(Bs + srow * ST + scol)     = p0b0;
        *(uint4*)(Bs + srow * ST + scol + 8) = p0b1;
        p0a0 = p1a0; p0a1 = p1a1; p0b0 = p1b0; p0b1 = p1b1;
        if (kt + 2 < 16) GLOAD(p1a0, p1a1, p1b0, p1b1, kt + 2)
        __syncthreads();
        #pragma unroll
        for (int kk = 0; kk < 4; ++kk) {
          bh8 af = *(const bh8*)(As + (wr * 16 + frow) * ST + kk * 32 + fk);
          bh8 b0 = *(const bh8*)(Bs + (wc * 32 + frow) * ST + kk * 32 + fk);
          bh8 b1 = *(const bh8*)(Bs + (wc * 32 + 16 + frow) * ST + kk * 32 + fk);
          acc0 = __builtin_amdgcn_mfma_f32_16x16x32_bf16(af, b0, acc0, 0, 0, 0);
          acc1 = __builtin_amdgcn_mfma_f32_16x16x32_bf16(af, b1, acc1, 0, 0, 0);
        }
        cur ^= 1;
      }
      #undef GLOAD
      __syncthreads();
      float* a_lds = (float*)smem;                     // [64][65] f32, bytes 0..16640
      unsigned short* xp = smem + 10240;               // [64][68] shorts, bytes 20480..
      {
        int r0 = wr * 16 + (lane >> 4) * 4;
        int c0 = wc * 32 + frow;
        #pragma unroll
        for (int reg = 0; reg < 4; ++reg) {
          a_lds[(r0 + reg) * 65 + c0]      = acc0[reg];
          a_lds[(r0 + reg) * 65 + c0 + 16] = acc1[reg];
        }
        *(uint4*)(xp + srow * 68 + (tid & 7) * 8) = xq;
      }
      __syncthreads();
      #pragma unroll
      for (int r = 0; r < 2; ++r) {
        int it = r * 512 + tid;
        int row = it >> 4, gl = it & 15;
        int n = nbase + row;
        int g = j0 + gl;
        float cold = (r == 0) ? creg0 : creg1;
        float pre[4];
        #pragma unroll
        for (int q = 0; q < 4; ++q) {
          float bq = (r == 0) ? br0[q] : br1[q];
          pre[q] = a_lds[row * 65 + q * 16 + gl] + b2f(xp[row * 68 + q * 16 + gl]) + bq;
        }
        float si = 1.0f / (1.0f + __expf(-pre[0]));
        float sf = 1.0f / (1.0f + __expf(-pre[1]));
        float so = 1.0f / (1.0f + __expf(-pre[2]));
        float tg = 2.0f / (1.0f + __expf(-2.0f * pre[3])) - 1.0f;
        float cn2 = sf * cold + si * tg;
        float hn = so * (2.0f / (1.0f + __expf(-2.0f * cn2)) - 1.0f);
        if (r == 0) creg0 = cn2; else creg1 = cn2;
        out[((size_t)n * T_S + t) * 1024 + g] = hn;
        hxn[(size_t)n * 2048 + g] = f2b(hn);
      }
    }
    nb += 1; gbar(bar, nb * 256);
  }
}

// ======================= TIER 0 fallback =======================

__global__ __launch_bounds__(256) void k_prep_w(
    const float* __restrict__ Wx, const float* __restrict__ Wh,
    const float* __restrict__ Wa, unsigned short* __restrict__ WT) {
  __shared__ float tile[64][65];
  int j0 = blockIdx.x * 64;
  int k0 = blockIdx.y * 64;
  const float* src; int kk0;
  if (k0 < 1024)      { src = Wx; kk0 = k0; }
  else if (k0 < 2048) { src = Wh; kk0 = k0 - 1024; }
  else                { src = Wa; kk0 = k0 - 2048; }
  for (int i = threadIdx.x; i < 4096; i += 256) {
    int r = i >> 6, c = i & 63;
    tile[r][c] = src[(size_t)(kk0 + r) * 4096 + (j0 + c)];
  }
  __syncthreads();
  for (int i = threadIdx.x; i < 4096; i += 256) {
    int r = i >> 6, c = i & 63;
    WT[(size_t)(j0 + r) * 3072 + (k0 + c)] = f2b(tile[c][r]);
  }
}

__global__ __launch_bounds__(256) void k_attn(
    const float* __restrict__ A, const unsigned short* __restrict__ hb,
    unsigned short* __restrict__ attnb) {
  int n = blockIdx.x;
  int tid = threadIdx.x;
  int lane = tid & 63, wave = tid >> 6;
  float areg[4][16];
  float s[16];
  #pragma unroll
  for (int p = 0; p < 16; ++p) s[p] = 0.f;
  #pragma unroll
  for (int r = 0; r < 4; ++r) {
    int h = r * 256 + tid;
    size_t base = (size_t)n * 1024 + h;
    const float4* a4 = (const float4*)(A + base * 16);
    #pragma unroll
    for (int q = 0; q < 4; ++q) {
      float4 v = a4[q];
      areg[r][q*4+0] = v.x; areg[r][q*4+1] = v.y;
      areg[r][q*4+2] = v.z; areg[r][q*4+3] = v.w;
    }
    float hv = b2f(hb[base]);
    #pragma unroll
    for (int p = 0; p < 16; ++p) s[p] += hv * areg[r][p];
  }
  #pragma unroll
  for (int p = 0; p < 16; ++p) {
    float v = s[p];
    #pragma unroll
    for (int off = 32; off > 0; off >>= 1) v += __shfl_xor(v, off);
    s[p] = v;
  }
  __shared__ float red[4][16];
  __shared__ float sc_sh[16];
  if (lane == 0) {
    #pragma unroll
    for (int p = 0; p < 16; ++p) red[wave][p] = s[p];
  }
  __syncthreads();
  if (tid < 16) {
    sc_sh[tid] = (red[0][tid] + red[1][tid] + red[2][tid] + red[3][tid]) * 0.03125f;
  }
  __syncthreads();
  float sc[16];
  #pragma unroll
  for (int p = 0; p < 16; ++p) sc[p] = sc_sh[p];
  float m = sc[0];
  #pragma unroll
  for (int p = 1; p < 16; ++p) m = fmaxf(m, sc[p]);
  float e[16]; float sum = 0.f;
  #pragma unroll
  for (int p = 0; p < 16; ++p) { e[p] = __expf(sc[p] - m); sum += e[p]; }
  float inv = 1.0f / sum;
  #pragma unroll
  for (int r = 0; r < 4; ++r) {
    float a = 0.f;
    #pragma unroll
    for (int p = 0; p < 16; ++p) a += areg[r][p] * e[p];
    attnb[(size_t)n * 1024 + r * 256 + tid] = f2b(a * inv);
  }
}

__global__ __launch_bounds__(512) void k_step(
    const unsigned short* __restrict__ xb,
    const unsigned short* __restrict__ WT,
    const float* __restrict__ bias,
    const unsigned short* __restrict__ hr,
    const unsigned short* __restrict__ atb,
    unsigned short* __restrict__ hw,
    float* __restrict__ cst,
    float* __restrict__ out,
    int t)
{
  __shared__ __align__(16) unsigned short smem[18432];
  int tid = threadIdx.x;
  int bn = blockIdx.x;
  int bm = blockIdx.y;
  int lane = tid & 63;
  int wave = tid >> 6;
  int wr = wave >> 1;
  int wc = wave & 1;
  int nbase = bm * 64;
  int j0 = bn * 16;
  int srow = tid >> 3;
  int scol = (tid & 7) * 8;
  int bj = ((srow >> 4) * 1024) + j0 + (srow & 15);
  const unsigned short* bsrc = WT + (size_t)bj * 3072 + scol;
  f32x4 acc0 = {0.f, 0.f, 0.f, 0.f};
  f32x4 acc1 = {0.f, 0.f, 0.f, 0.f};
  uint4 ra, rb;
  auto gload = [&](int kt) {
    int k0 = kt * 64;
    const unsigned short* src; size_t rs; int kloc;
    if (k0 < 1024)      { src = xb + (size_t)t * 1024; rs = (size_t)T_S * 1024; kloc = k0; }
    else if (k0 < 2048) { src = hr;  rs = 1024; kloc = k0 - 1024; }
    else                { src = atb; rs = 1024; kloc = k0 - 2048; }
    ra = *(const uint4*)(src + (size_t)(nbase + srow) * rs + kloc + scol);
    rb = *(const uint4*)(bsrc + k0);
  };
  int frow = lane & 15;
  int fk = (lane >> 4) * 8;
  gload(0);
  int cur = 0;
  for (int kt = 0; kt < 48; ++kt) {
    unsigned short* As = smem + cur * 4608;
    unsigned short* Bs = smem + 9216 + cur * 4608;
    *(uint4*)(As + srow * 72 + scol) = ra;
    *(uint4*)(Bs + srow * 72 + scol) = rb;
    __syncthreads();
    if (kt + 1 < 48) gload(kt + 1);
    #pragma unroll
    for (int kk = 0; kk < 2; ++kk) {
      bh8 af  = *(const bh8*)(As + (wr * 16 + frow) * 72 + kk * 32 + fk);
      bh8 bf0 = *(const bh8*)(Bs + (wc * 32 + frow) * 72 + kk * 32 + fk);
      bh8 bf1 = *(const bh8*)(Bs + (wc * 32 + 16 + frow) * 72 + kk * 32 + fk);
      acc0 = __builtin_amdgcn_mfma_f32_16x16x32_bf16(af, bf0, acc0, 0, 0, 0);
      acc1 = __builtin_amdgcn_mfma_f32_16x16x32_bf16(af, bf1, acc1, 0, 0, 0);
    }
    cur ^= 1;
  }
  __syncthreads();
  float* a_lds = (float*)smem;
  {
    int r0 = wr * 16 + (lane >> 4) * 4;
    int c0 = wc * 32 + frow;
    #pragma unroll
    for (int reg = 0; reg < 4; ++reg) {
      a_lds[(r0 + reg) * 65 + c0]      = acc0[reg];
      a_lds[(r0 + reg) * 65 + c0 + 16] = acc1[reg];
    }
  }
  __syncthreads();
  #pragma unroll
  for (int r = 0; r < 2; ++r) {
    int pi = r * 512 + tid;
    int row = pi >> 4, gl = pi & 15;
    int n = nbase + row;
    int g = j0 + gl;
    float ii = a_lds[row * 65 + gl]      + bias[g];
    float ff = a_lds[row * 65 + 16 + gl] + bias[1024 + g];
    float oo = a_lds[row * 65 + 32 + gl] + bias[2048 + g];
    float gg = a_lds[row * 65 + 48 + gl] + bias[3072 + g];
    size_t ci = (size_t)n * 1024 + g;
    float cold = cst[ci];
    float si = 1.0f / (1.0f + __expf(-ii));
    float sf = 1.0f / (1.0f + __expf(-ff));
    float so = 1.0f / (1.0f + __expf(-oo));
    float tg = 2.0f / (1.0f + __expf(-2.0f * gg)) - 1.0f;
    float cn = sf * cold + si * tg;
    float hn = so * (2.0f / (1.0f + __expf(-2.0f * cn)) - 1.0f);
    cst[ci] = cn;
    out[((size_t)n * T_S + t) * 1024 + g] = hn;
    hw[ci] = f2b(hn);
  }
}

// ======================= host =======================

extern "C" void kernel_launch(void* const* d_in, const int* in_sizes, int n_in,
                              void* d_out, int out_size, void* d_ws, size_t ws_size,
                              hipStream_t stream) {
  const float* x  = (const float*)d_in[0];
  const float* A  = (const float*)d_in[1];
  const float* Wx = (const float*)d_in[2];
  const float* Wh = (const float*)d_in[3];
  const float* Wa = (const float*)d_in[4];
  const float* b  = (const float*)d_in[5];
  float* out = (float*)d_out;
  char* ws = (char*)d_ws;

  if (ws_size >= 204472576ull) {
    // ---- Tier 3: persistent step loop ----
    unsigned short* WxT   = (unsigned short*)(ws);              //   8,388,608
    unsigned short* PW    = (unsigned short*)(ws + 8388608);    //  16,777,216
    unsigned short* xb2   = (unsigned short*)(ws + 25165824);   //  33,554,432
    unsigned short* Ab    = (unsigned short*)(ws + 58720256);   //   8,388,608
    unsigned short* xprojP= (unsigned short*)(ws + 67108864);   // 134,217,728
    unsigned short* hxA   = (unsigned short*)(ws + 201326592);  //   1,048,576
    unsigned short* hxB   = (unsigned short*)(ws + 202375168);  //   1,048,576
    float* cst            = (float*)(ws + 203423744);           //   1,048,576
    int* bar              = (int*)(ws + 204472320);             //         256

    hipFuncSetAttribute((const void*)k_steps,
                        hipFuncAttributeMaxDynamicSharedMemorySize, 86016);

    k_tw3<<<dim3(64, 16, 3), 256, 0, stream>>>(Wx, Wh, Wa, WxT, PW);
    k_conv_x2<<<4096, 256, 0, stream>>>(x, xb2);
    k_conv<<<1024, 256, 0, stream>>>(A, Ab, 1048576);
    k_init2<<<1024, 256, 0, stream>>>(A, hxA, cst);
    k_gemm_t<1><<<dim3(128, 32), 512, 0, stream>>>(xb2, WxT, xprojP);
    hipMemsetAsync(bar, 0, 256, stream);
    k_steps<<<256, 512, 86016, stream>>>(Ab, PW, xprojP, b, hxA, hxB, cst, out, bar);
  } else if (ws_size >= 61341696ull) {
    // ---- Tier 0 fallback ----
    unsigned short* WT  = (unsigned short*)(ws);
    unsigned short* xb  = (unsigned short*)(ws + 25165824);
    unsigned short* hA  = (unsigned short*)(ws + 58720256);
    unsigned short* hB  = (unsigned short*)(ws + 59244544);
    unsigned short* atb = (unsigned short*)(ws + 59768832);
    float* cst          = (float*)(ws + 60293120);

    k_prep_w<<<dim3(64, 48), 256, 0, stream>>>(Wx, Wh, Wa, WT);
    k_conv<<<2048, 256, 0, stream>>>(x, xb, 4194304);
    k_init1<<<1024, 256, 0, stream>>>(A, hA, cst);
    for (int t = 0; t < 64; ++t) {
      const unsigned short* hr = (t & 1) ? hB : hA;
      unsigned short* hwv      = (t & 1) ? hA : hB;
      k_attn<<<256, 256, 0, stream>>>(A, hr, atb);
      k_step<<<dim3(64, 4), 512, 0, stream>>>(xb, WT, b, hr, atb, hwv, cst, out, t);
    }
  }
}

// Round 8
// 1330.923 us; speedup vs baseline: 4.0797x; 4.0797x over previous
//
#include <hip/hip_runtime.h>
#include <cstdint>
#include <cstddef>

#define T_S 64

typedef __attribute__((ext_vector_type(4))) float f32x4;
typedef __attribute__((ext_vector_type(2))) float f32x2;
typedef __attribute__((ext_vector_type(8))) short bh8;

__device__ __forceinline__ unsigned short f2b(float f) {
  uint32_t x = __builtin_bit_cast(uint32_t, f);
  uint32_t r = (x + 0x7FFFu + ((x >> 16) & 1u)) >> 16;
  return (unsigned short)r;
}
__device__ __forceinline__ float b2f(unsigned short u) {
  uint32_t v = ((uint32_t)u) << 16;
  return __builtin_bit_cast(float, v);
}

// L3-coherent (bypass-L2) access helpers: sc0 sc1 on gfx950 reads/writes the
// device coherence point, so cross-XCD visibility needs NO cache invalidates.
__device__ __forceinline__ unsigned ld_u32_l3(const void* p) {
  unsigned r;
  asm volatile("global_load_dword %0, %1, off sc0 sc1\n\ts_waitcnt vmcnt(0)"
               : "=v"(r) : "v"(p) : "memory");
  return r;
}
__device__ __forceinline__ void st_u32_l3(void* p, unsigned v) {
  asm volatile("global_store_dword %0, %1, off sc0 sc1" :: "v"(p), "v"(v) : "memory");
}

// group barrier: atomic add at L3 (sc1), poll with sc0 sc1 loads (L3-fresh,
// never invalidates local L2). Entry __syncthreads drains each wave's vmem
// (compiler inserts vmcnt(0)) so all sc1 stores are L3-visible before arrive.
__device__ __forceinline__ void gbar(int* bar, int target) {
  __syncthreads();
  if (threadIdx.x == 0) {
    int one = 1;
    asm volatile("s_waitcnt vmcnt(0)\n\t"
                 "global_atomic_add %0, %1, off sc1"
                 :: "v"(bar), "v"(one) : "memory");
    int v;
    do {
      __builtin_amdgcn_s_sleep(1);
      asm volatile("global_load_dword %0, %1, off sc0 sc1\n\ts_waitcnt vmcnt(0)"
                   : "=v"(v) : "v"(bar) : "memory");
    } while (v < target);
  }
  __syncthreads();
}

// ======================= prep =======================

__global__ void k_conv(const float* __restrict__ src, unsigned short* __restrict__ dst, int n4) {
  int i = blockIdx.x * blockDim.x + threadIdx.x;
  int stride = gridDim.x * blockDim.x;
  for (; i < n4; i += stride) {
    float4 v = ((const float4*)src)[i];
    ushort4 o; o.x = f2b(v.x); o.y = f2b(v.y); o.z = f2b(v.z); o.w = f2b(v.w);
    ((ushort4*)dst)[i] = o;
  }
}

// z=0 Wx -> WxT[4096][1024]; z=1/2 Wh/Wa -> PW[4096][2048] with row order
// prow = (hcol>>5)*128 + q*32 + (hcol&31)  for gate col = q*1024 + hcol.
__global__ __launch_bounds__(256) void k_tw3(
    const float* __restrict__ Wx, const float* __restrict__ Wh,
    const float* __restrict__ Wa,
    unsigned short* __restrict__ WxT, unsigned short* __restrict__ PW) {
  __shared__ float tile[64][65];
  int j0 = blockIdx.x * 64;
  int k0 = blockIdx.y * 64;
  int z = blockIdx.z;
  const float* src = (z == 0) ? Wx : (z == 1) ? Wh : Wa;
  for (int i = threadIdx.x; i < 4096; i += 256) {
    int r = i >> 6, c = i & 63;
    tile[r][c] = src[(size_t)(k0 + r) * 4096 + (j0 + c)];
  }
  __syncthreads();
  for (int i = threadIdx.x; i < 4096; i += 256) {
    int r = i >> 6, c = i & 63;
    int col = j0 + r;
    unsigned short v = f2b(tile[c][r]);
    if (z == 0) {
      WxT[(size_t)col * 1024 + (k0 + c)] = v;
    } else {
      int q = col >> 10, hcol = col & 1023;
      int prow = (hcol >> 5) * 128 + q * 32 + (hcol & 31);
      PW[(size_t)prow * 2048 + (size_t)(z - 1) * 1024 + (k0 + c)] = v;
    }
  }
}

// xb2[(t*256+n)][k] = bf16(x[n][t][k])
__global__ __launch_bounds__(256) void k_conv_x2(
    const float* __restrict__ x, unsigned short* __restrict__ xb2) {
  int b = blockIdx.x, tid = threadIdx.x;
  #pragma unroll
  for (int rr = 0; rr < 4; ++rr) {
    int r = b * 4 + rr;
    int t = r >> 8, n = r & 255;
    const float4* src = (const float4*)(x + ((size_t)n * 64 + t) * 1024);
    float4 v = src[tid];
    ushort4 o; o.x = f2b(v.x); o.y = f2b(v.y); o.z = f2b(v.z); o.w = f2b(v.w);
    ((ushort4*)(xb2 + (size_t)r * 1024))[tid] = o;
  }
}

// h0 = c0 = mean(A over 16); h -> hx[n][0..1024) row stride 2048
__global__ __launch_bounds__(256) void k_init2(
    const float* __restrict__ A, unsigned short* __restrict__ hx,
    float* __restrict__ cst) {
  int idx = blockIdx.x * 256 + threadIdx.x;
  const float4* a4 = (const float4*)(A + (size_t)idx * 16);
  float s = 0.f;
  #pragma unroll
  for (int q = 0; q < 4; ++q) { float4 v = a4[q]; s += v.x + v.y + v.z + v.w; }
  s *= 0.0625f;
  cst[idx] = s;
  hx[(size_t)(idx >> 10) * 2048 + (idx & 1023)] = f2b(s);
}

// Tier-0 h0 (row stride 1024)
__global__ __launch_bounds__(256) void k_init1(
    const float* __restrict__ A, unsigned short* __restrict__ hb,
    float* __restrict__ cst) {
  int idx = blockIdx.x * 256 + threadIdx.x;
  const float4* a4 = (const float4*)(A + (size_t)idx * 16);
  float s = 0.f;
  #pragma unroll
  for (int q = 0; q < 4; ++q) { float4 v = a4[q]; s += v.x + v.y + v.z + v.w; }
  s *= 0.0625f;
  cst[idx] = s;
  hb[idx] = f2b(s);
}

// C = A[M][1024] @ Bt[4096][1024]^T. PERM=1: xprojP layout
// off = row*4096 + (hcol>>5)*128 + q*32 + (hcol&31), col = q*1024 + hcol
template <int PERM>
__global__ __launch_bounds__(512) void k_gemm_t(
    const unsigned short* __restrict__ Asrc,
    const unsigned short* __restrict__ Bt,
    unsigned short* __restrict__ C) {
  __shared__ __align__(16) unsigned short smem[36864];
  int tid = threadIdx.x;
  int bx = blockIdx.x, by = blockIdx.y;
  int lane = tid & 63, wave = tid >> 6;
  int wr = wave >> 1, wc = wave & 1;
  int srow = tid >> 3;
  int scol = (tid & 7) * 8;
  const unsigned short* arow0 = Asrc + ((size_t)(bx * 128 + srow)) * 1024 + scol;
  const unsigned short* arow1 = arow0 + (size_t)64 * 1024;
  const unsigned short* brow0 = Bt + ((size_t)(by * 128 + srow)) * 1024 + scol;
  const unsigned short* brow1 = brow0 + (size_t)64 * 1024;

  f32x4 acc[2][4];
  #pragma unroll
  for (int m = 0; m < 2; ++m)
    #pragma unroll
    for (int nn = 0; nn < 4; ++nn) acc[m][nn] = {0.f, 0.f, 0.f, 0.f};

  uint4 ra0, ra1, rb0, rb1;
  auto gload = [&](int kt) {
    int k0 = kt * 64;
    ra0 = *(const uint4*)(arow0 + k0);
    ra1 = *(const uint4*)(arow1 + k0);
    rb0 = *(const uint4*)(brow0 + k0);
    rb1 = *(const uint4*)(brow1 + k0);
  };
  int frow = lane & 15, fk = (lane >> 4) * 8;
  gload(0);
  int cur = 0;
  for (int kt = 0; kt < 16; ++kt) {
    unsigned short* As = smem + cur * 18432;
    unsigned short* Bs = As + 9216;
    *(uint4*)(As + srow * 72 + scol) = ra0;
    *(uint4*)(As + (srow + 64) * 72 + scol) = ra1;
    *(uint4*)(Bs + srow * 72 + scol) = rb0;
    *(uint4*)(Bs + (srow + 64) * 72 + scol) = rb1;
    __syncthreads();
    if (kt + 1 < 16) gload(kt + 1);
    #pragma unroll
    for (int kk = 0; kk < 2; ++kk) {
      bh8 af[2], bf[4];
      #pragma unroll
      for (int m = 0; m < 2; ++m)
        af[m] = *(const bh8*)(As + (wr * 32 + m * 16 + frow) * 72 + kk * 32 + fk);
      #pragma unroll
      for (int nn = 0; nn < 4; ++nn)
        bf[nn] = *(const bh8*)(Bs + (wc * 64 + nn * 16 + frow) * 72 + kk * 32 + fk);
      #pragma unroll
      for (int m = 0; m < 2; ++m)
        #pragma unroll
        for (int nn = 0; nn < 4; ++nn)
          acc[m][nn] = __builtin_amdgcn_mfma_f32_16x16x32_bf16(af[m], bf[nn], acc[m][nn], 0, 0, 0);
    }
    cur ^= 1;
  }
  int rbase = bx * 128 + wr * 32 + (lane >> 4) * 4;
  int cbase = by * 128 + wc * 64 + frow;
  #pragma unroll
  for (int m = 0; m < 2; ++m)
    #pragma unroll
    for (int nn = 0; nn < 4; ++nn)
      #pragma unroll
      for (int reg = 0; reg < 4; ++reg) {
        size_t row = rbase + m * 16 + reg;
        int c = cbase + nn * 16;
        int q = c >> 10, hcol = c & 1023;
        size_t off = PERM ? ((size_t)row * 4096 + (hcol >> 5) * 128 + q * 32 + (hcol & 31))
                          : ((size_t)row * 4096 + c);
        C[off] = f2b(acc[m][nn][reg]);
      }
}

// ======================= persistent step loop =======================
// 256 blocks = 8 groups x 32. Group g owns rows [g*32,g*32+32). Block (g,j):
//   S+T: attention for row n = g*32+j  (hx via L3)
//   G:   32 rows x 128 gate-cols (j's slice), K=2048, depth-4 counted-vmcnt
//        pipeline, XOR-swizzled LDS, raw s_barrier (no vmcnt drain).
__global__ __launch_bounds__(512, 1) void k_steps(
    const unsigned short* __restrict__ Ab,     // [256][1024][16]
    const unsigned short* __restrict__ PW,     // [4096][2048], j*128+q*32+l major
    const unsigned short* __restrict__ xprojP, // [(t*256+n)][j*128+q*32+l]
    const float* __restrict__ bias,
    unsigned short* __restrict__ hxA,          // [256][2048] = [h|attn]
    unsigned short* __restrict__ hxB,
    const float* __restrict__ cst0,
    float* __restrict__ out,
    int* __restrict__ bars) {
  extern __shared__ __align__(16) char sm[];
  const int tid = threadIdx.x;
  const int bid = blockIdx.x;
  const int lane = tid & 63, wave = tid >> 6;
  const int wm = wave & 1, wc = wave >> 1;
  const int frow = lane & 15, fg = lane >> 4;
  const int g = bid >> 5, j = bid & 31;
  const int nbase = g * 32;
  const int nA = nbase + j;
  int* mybar = bars + (g << 6);   // 256B-spaced per-group counters

  const int erow = tid >> 4;          // 0..31: epilogue row, A-stage row, xp row
  const int el2 = (tid & 15) * 2;
  const int hcol = j * 32 + el2;

  // persistent per-thread state
  float creg[2];
  float brg[4][2];
  {
    const float* cp = cst0 + (size_t)(nbase + erow) * 1024 + hcol;
    creg[0] = cp[0]; creg[1] = cp[1];
    #pragma unroll
    for (int q = 0; q < 4; ++q) {
      brg[q][0] = bias[q * 1024 + hcol];
      brg[q][1] = bias[q * 1024 + hcol + 1];
    }
  }

  // staging global bases (byte pointers; per-kt offset = kt*256 via imm)
  const int c16 = (tid & 15) * 16;
  const char* bB0 = (const char*)(PW + (size_t)(j * 128 + erow) * 2048) + c16;
  const char* bB1 = bB0 + 32 * 4096;
  const char* bB2 = bB0 + 64 * 4096;
  const char* bB3 = bB0 + 96 * 4096;
  const char* aBA = (const char*)(hxA + (size_t)(nbase + erow) * 2048) + c16;
  const char* aBB = (const char*)(hxB + (size_t)(nbase + erow) * 2048) + c16;

  // swizzled LDS offsets (bytes). Buffers: [A 8KB][B 32KB] x2 at 0 / 40960.
  const int wA = (erow * 256 + c16) ^ ((erow & 7) << 4);
  const int qA = ((wm * 16 + frow) * 256 + fg * 16) ^ ((frow & 7) << 4);
  const int qB = ((wc * 32 + frow) * 256 + fg * 16) ^ ((frow & 7) << 4);

  uint4 sa0, sa1, sa2, sa3;
  uint4 sb00, sb01, sb02, sb03;
  uint4 sb10, sb11, sb12, sb13;
  uint4 sb20, sb21, sb22, sb23;
  uint4 sb30, sb31, sb32, sb33;

#define LOADST(st, ktL) \
  asm volatile("global_load_dwordx4 %0, %1, off offset:%c2 sc0 sc1" : "=v"(sa##st) : "v"(aB), "i"((ktL) * 256)); \
  asm volatile("global_load_dwordx4 %0, %1, off offset:%c2" : "=v"(sb##st##0) : "v"(bB0), "i"((ktL) * 256)); \
  asm volatile("global_load_dwordx4 %0, %1, off offset:%c2" : "=v"(sb##st##1) : "v"(bB1), "i"((ktL) * 256)); \
  asm volatile("global_load_dwordx4 %0, %1, off offset:%c2" : "=v"(sb##st##2) : "v"(bB2), "i"((ktL) * 256)); \
  asm volatile("global_load_dwordx4 %0, %1, off offset:%c2" : "=v"(sb##st##3) : "v"(bB3), "i"((ktL) * 256));

#define GSTEP(kt, st, bufo, WN) { \
  asm volatile("s_waitcnt vmcnt(" #WN ")" ::: "memory"); \
  *(uint4*)(sm + (bufo) + wA) = sa##st; \
  *(uint4*)(sm + (bufo) + 8192 + wA) = sb##st##0; \
  *(uint4*)(sm + (bufo) + 8192 + wA + 8192) = sb##st##1; \
  *(uint4*)(sm + (bufo) + 8192 + wA + 16384) = sb##st##2; \
  *(uint4*)(sm + (bufo) + 8192 + wA + 24576) = sb##st##3; \
  if ((kt) + 4 < 16) { LOADST(st, (kt) + 4) } \
  asm volatile("s_waitcnt lgkmcnt(0)" ::: "memory"); \
  __builtin_amdgcn_s_barrier(); \
  _Pragma("unroll") \
  for (int kk = 0; kk < 4; ++kk) { \
    bh8 af  = *(const bh8*)(sm + (bufo) + (qA ^ (kk << 6))); \
    bh8 bf0 = *(const bh8*)(sm + (bufo) + 8192 + (qB ^ (kk << 6))); \
    bh8 bf1 = *(const bh8*)(sm + (bufo) + 8192 + 4096 + (qB ^ (kk << 6))); \
    acc0 = __builtin_amdgcn_mfma_f32_16x16x32_bf16(af, bf0, acc0, 0, 0, 0); \
    acc1 = __builtin_amdgcn_mfma_f32_16x16x32_bf16(af, bf1, acc1, 0, 0, 0); \
  } \
}

  int nb = 0;
  for (int t = 0; t < 64; ++t) {
    unsigned short* hxc = (t & 1) ? hxB : hxA;
    unsigned short* hxn = (t & 1) ? hxA : hxB;
    const char* aB = (t & 1) ? aBB : aBA;

    // ---------- Phase S+T: attention for n = nA ----------
    {
      unsigned hh = ld_u32_l3(hxc + (size_t)nA * 2048 + tid * 2);
      float hv0 = b2f((unsigned short)(hh & 0xffff));
      float hv1 = b2f((unsigned short)(hh >> 16));
      const unsigned short* ap = Ab + (size_t)nA * 16384 + tid * 32;
      bh8 a0 = *(const bh8*)(ap);
      bh8 a1 = *(const bh8*)(ap + 8);
      bh8 a2 = *(const bh8*)(ap + 16);
      bh8 a3 = *(const bh8*)(ap + 24);
      float s[16];
      #pragma unroll
      for (int p = 0; p < 8; ++p) {
        s[p]     = hv0 * b2f((unsigned short)a0[p]) + hv1 * b2f((unsigned short)a2[p]);
        s[8 + p] = hv0 * b2f((unsigned short)a1[p]) + hv1 * b2f((unsigned short)a3[p]);
      }
      #pragma unroll
      for (int p = 0; p < 16; ++p) {
        float v = s[p];
        #pragma unroll
        for (int off = 32; off > 0; off >>= 1) v += __shfl_xor(v, off);
        s[p] = v;
      }
      float* red = (float*)sm;     // [8][16]
      float* scs = red + 128;      // [16]
      if (lane == 0) {
        #pragma unroll
        for (int p = 0; p < 16; ++p) red[wave * 16 + p] = s[p];
      }
      __syncthreads();
      if (tid < 16) {
        float v = 0.f;
        #pragma unroll
        for (int wv = 0; wv < 8; ++wv) v += red[wv * 16 + tid];
        scs[tid] = v * 0.03125f;
      }
      __syncthreads();
      float sc[16];
      #pragma unroll
      for (int p = 0; p < 16; ++p) sc[p] = scs[p];
      float m = sc[0];
      #pragma unroll
      for (int p = 1; p < 16; ++p) m = fmaxf(m, sc[p]);
      float w[16]; float sum = 0.f;
      #pragma unroll
      for (int p = 0; p < 16; ++p) { w[p] = __expf(sc[p] - m); sum += w[p]; }
      float inv = 1.0f / sum;
      float at0 = 0.f, at1 = 0.f;
      #pragma unroll
      for (int p = 0; p < 8; ++p) {
        at0 += w[p] * b2f((unsigned short)a0[p]) + w[8 + p] * b2f((unsigned short)a1[p]);
        at1 += w[p] * b2f((unsigned short)a2[p]) + w[8 + p] * b2f((unsigned short)a3[p]);
      }
      at0 *= inv; at1 *= inv;
      unsigned packed = (unsigned)f2b(at0) | ((unsigned)f2b(at1) << 16);
      st_u32_l3(hxc + (size_t)nA * 2048 + 1024 + tid * 2, packed);
    }
    nb += 1; gbar(mybar, nb * 32);

    // ---------- Phase G ----------
    {
      uint4 xq = *(const uint4*)(xprojP + ((size_t)(t * 256 + nbase + erow)) * 4096
                                 + j * 128 + (tid & 15) * 8);
      f32x4 acc0 = {0.f, 0.f, 0.f, 0.f};
      f32x4 acc1 = {0.f, 0.f, 0.f, 0.f};
      LOADST(0, 0) LOADST(1, 1) LOADST(2, 2) LOADST(3, 3)
      GSTEP(0, 0, 0, 15)      GSTEP(1, 1, 40960, 15)
      GSTEP(2, 2, 0, 15)      GSTEP(3, 3, 40960, 15)
      GSTEP(4, 0, 0, 15)      GSTEP(5, 1, 40960, 15)
      GSTEP(6, 2, 0, 15)      GSTEP(7, 3, 40960, 15)
      GSTEP(8, 0, 0, 15)      GSTEP(9, 1, 40960, 15)
      GSTEP(10, 2, 0, 15)     GSTEP(11, 3, 40960, 15)
      GSTEP(12, 0, 0, 15)     GSTEP(13, 1, 40960, 10)
      GSTEP(14, 2, 0, 5)      GSTEP(15, 3, 40960, 0)
      __syncthreads();
      float* a_lds = (float*)sm;                       // [32][132] f32
      unsigned short* xp = (unsigned short*)(sm + 16896); // [32][136] shorts
      {
        int r0 = wm * 16 + fg * 4;
        int c0 = wc * 32 + frow;
        #pragma unroll
        for (int r = 0; r < 4; ++r) {
          a_lds[(r0 + r) * 132 + c0]      = acc0[r];
          a_lds[(r0 + r) * 132 + c0 + 16] = acc1[r];
        }
        *(uint4*)(xp + erow * 136 + (tid & 15) * 8) = xq;
      }
      __syncthreads();
      {
        float h2[2];
        #pragma unroll
        for (int e = 0; e < 2; ++e) {
          float pre[4];
          #pragma unroll
          for (int q = 0; q < 4; ++q)
            pre[q] = a_lds[erow * 132 + q * 32 + el2 + e]
                   + b2f(xp[erow * 136 + q * 32 + el2 + e]) + brg[q][e];
          float si = 1.0f / (1.0f + __expf(-pre[0]));
          float sf = 1.0f / (1.0f + __expf(-pre[1]));
          float so = 1.0f / (1.0f + __expf(-pre[2]));
          float tg = 2.0f / (1.0f + __expf(-2.0f * pre[3])) - 1.0f;
          float cn = sf * creg[e] + si * tg;
          creg[e] = cn;
          h2[e] = so * (2.0f / (1.0f + __expf(-2.0f * cn)) - 1.0f);
        }
        f32x2 o2 = {h2[0], h2[1]};
        __builtin_nontemporal_store(o2,
            (f32x2*)(out + ((size_t)(nbase + erow) * T_S + t) * 1024 + hcol));
        unsigned hp = (unsigned)f2b(h2[0]) | ((unsigned)f2b(h2[1]) << 16);
        st_u32_l3(hxn + (size_t)(nbase + erow) * 2048 + hcol, hp);
      }
    }
    nb += 1; gbar(mybar, nb * 32);
  }
#undef GSTEP
#undef LOADST
}

// ======================= TIER 0 fallback =======================

__global__ __launch_bounds__(256) void k_prep_w(
    const float* __restrict__ Wx, const float* __restrict__ Wh,
    const float* __restrict__ Wa, unsigned short* __restrict__ WT) {
  __shared__ float tile[64][65];
  int j0 = blockIdx.x * 64;
  int k0 = blockIdx.y * 64;
  const float* src; int kk0;
  if (k0 < 1024)      { src = Wx; kk0 = k0; }
  else if (k0 < 2048) { src = Wh; kk0 = k0 - 1024; }
  else                { src = Wa; kk0 = k0 - 2048; }
  for (int i = threadIdx.x; i < 4096; i += 256) {
    int r = i >> 6, c = i & 63;
    tile[r][c] = src[(size_t)(kk0 + r) * 4096 + (j0 + c)];
  }
  __syncthreads();
  for (int i = threadIdx.x; i < 4096; i += 256) {
    int r = i >> 6, c = i & 63;
    WT[(size_t)(j0 + r) * 3072 + (k0 + c)] = f2b(tile[c][r]);
  }
}

__global__ __launch_bounds__(256) void k_attn(
    const float* __restrict__ A, const unsigned short* __restrict__ hb,
    unsigned short* __restrict__ attnb) {
  int n = blockIdx.x;
  int tid = threadIdx.x;
  int lane = tid & 63, wave = tid >> 6;
  float areg[4][16];
  float s[16];
  #pragma unroll
  for (int p = 0; p < 16; ++p) s[p] = 0.f;
  #pragma unroll
  for (int r = 0; r < 4; ++r) {
    int h = r * 256 + tid;
    size_t base = (size_t)n * 1024 + h;
    const float4* a4 = (const float4*)(A + base * 16);
    #pragma unroll
    for (int q = 0; q < 4; ++q) {
      float4 v = a4[q];
      areg[r][q*4+0] = v.x; areg[r][q*4+1] = v.y;
      areg[r][q*4+2] = v.z; areg[r][q*4+3] = v.w;
    }
    float hv = b2f(hb[base]);
    #pragma unroll
    for (int p = 0; p < 16; ++p) s[p] += hv * areg[r][p];
  }
  #pragma unroll
  for (int p = 0; p < 16; ++p) {
    float v = s[p];
    #pragma unroll
    for (int off = 32; off > 0; off >>= 1) v += __shfl_xor(v, off);
    s[p] = v;
  }
  __shared__ float red[4][16];
  __shared__ float sc_sh[16];
  if (lane == 0) {
    #pragma unroll
    for (int p = 0; p < 16; ++p) red[wave][p] = s[p];
  }
  __syncthreads();
  if (tid < 16) {
    sc_sh[tid] = (red[0][tid] + red[1][tid] + red[2][tid] + red[3][tid]) * 0.03125f;
  }
  __syncthreads();
  float sc[16];
  #pragma unroll
  for (int p = 0; p < 16; ++p) sc[p] = sc_sh[p];
  float m = sc[0];
  #pragma unroll
  for (int p = 1; p < 16; ++p) m = fmaxf(m, sc[p]);
  float e[16]; float sum = 0.f;
  #pragma unroll
  for (int p = 0; p < 16; ++p) { e[p] = __expf(sc[p] - m); sum += e[p]; }
  float inv = 1.0f / sum;
  #pragma unroll
  for (int r = 0; r < 4; ++r) {
    float a = 0.f;
    #pragma unroll
    for (int p = 0; p < 16; ++p) a += areg[r][p] * e[p];
    attnb[(size_t)n * 1024 + r * 256 + tid] = f2b(a * inv);
  }
}

__global__ __launch_bounds__(512) void k_step(
    const unsigned short* __restrict__ xb,
    const unsigned short* __restrict__ WT,
    const float* __restrict__ bias,
    const unsigned short* __restrict__ hr,
    const unsigned short* __restrict__ atb,
    unsigned short* __restrict__ hw,
    float* __restrict__ cst,
    float* __restrict__ out,
    int t)
{
  __shared__ __align__(16) unsigned short smem[18432];
  int tid = threadIdx.x;
  int bn = blockIdx.x;
  int bm = blockIdx.y;
  int lane = tid & 63;
  int wave = tid >> 6;
  int wr = wave >> 1;
  int wc = wave & 1;
  int nbase = bm * 64;
  int j0 = bn * 16;
  int srow = tid >> 3;
  int scol = (tid & 7) * 8;
  int bj = ((srow >> 4) * 1024) + j0 + (srow & 15);
  const unsigned short* bsrc = WT + (size_t)bj * 3072 + scol;
  f32x4 acc0 = {0.f, 0.f, 0.f, 0.f};
  f32x4 acc1 = {0.f, 0.f, 0.f, 0.f};
  uint4 ra, rb;
  auto gload = [&](int kt) {
    int k0 = kt * 64;
    const unsigned short* src; size_t rs; int kloc;
    if (k0 < 1024)      { src = xb + (size_t)t * 1024; rs = (size_t)T_S * 1024; kloc = k0; }
    else if (k0 < 2048) { src = hr;  rs = 1024; kloc = k0 - 1024; }
    else                { src = atb; rs = 1024; kloc = k0 - 2048; }
    ra = *(const uint4*)(src + (size_t)(nbase + srow) * rs + kloc + scol);
    rb = *(const uint4*)(bsrc + k0);
  };
  int frow = lane & 15;
  int fk = (lane >> 4) * 8;
  gload(0);
  int cur = 0;
  for (int kt = 0; kt < 48; ++kt) {
    unsigned short* As = smem + cur * 4608;
    unsigned short* Bs = smem + 9216 + cur * 4608;
    *(uint4*)(As + srow * 72 + scol) = ra;
    *(uint4*)(Bs + srow * 72 + scol) = rb;
    __syncthreads();
    if (kt + 1 < 48) gload(kt + 1);
    #pragma unroll
    for (int kk = 0; kk < 2; ++kk) {
      bh8 af  = *(const bh8*)(As + (wr * 16 + frow) * 72 + kk * 32 + fk);
      bh8 bf0 = *(const bh8*)(Bs + (wc * 32 + frow) * 72 + kk * 32 + fk);
      bh8 bf1 = *(const bh8*)(Bs + (wc * 32 + 16 + frow) * 72 + kk * 32 + fk);
      acc0 = __builtin_amdgcn_mfma_f32_16x16x32_bf16(af, bf0, acc0, 0, 0, 0);
      acc1 = __builtin_amdgcn_mfma_f32_16x16x32_bf16(af, bf1, acc1, 0, 0, 0);
    }
    cur ^= 1;
  }
  __syncthreads();
  float* a_lds = (float*)smem;
  {
    int r0 = wr * 16 + (lane >> 4) * 4;
    int c0 = wc * 32 + frow;
    #pragma unroll
    for (int reg = 0; reg < 4; ++reg) {
      a_lds[(r0 + reg) * 65 + c0]      = acc0[reg];
      a_lds[(r0 + reg) * 65 + c0 + 16] = acc1[reg];
    }
  }
  __syncthreads();
  #pragma unroll
  for (int r = 0; r < 2; ++r) {
    int pi = r * 512 + tid;
    int row = pi >> 4, gl = pi & 15;
    int n = nbase + row;
    int gcol = j0 + gl;
    float ii = a_lds[row * 65 + gl]      + bias[gcol];
    float ff = a_lds[row * 65 + 16 + gl] + bias[1024 + gcol];
    float oo = a_lds[row * 65 + 32 + gl] + bias[2048 + gcol];
    float gg = a_lds[row * 65 + 48 + gl] + bias[3072 + gcol];
    size_t ci = (size_t)n * 1024 + gcol;
    float cold = cst[ci];
    float si = 1.0f / (1.0f + __expf(-ii));
    float sf = 1.0f / (1.0f + __expf(-ff));
    float so = 1.0f / (1.0f + __expf(-oo));
    float tg = 2.0f / (1.0f + __expf(-2.0f * gg)) - 1.0f;
    float cn = sf * cold + si * tg;
    float hn = so * (2.0f / (1.0f + __expf(-2.0f * cn)) - 1.0f);
    cst[ci] = cn;
    out[((size_t)n * T_S + t) * 1024 + gcol] = hn;
    hw[ci] = f2b(hn);
  }
}

// ======================= host =======================

extern "C" void kernel_launch(void* const* d_in, const int* in_sizes, int n_in,
                              void* d_out, int out_size, void* d_ws, size_t ws_size,
                              hipStream_t stream) {
  const float* x  = (const float*)d_in[0];
  const float* A  = (const float*)d_in[1];
  const float* Wx = (const float*)d_in[2];
  const float* Wh = (const float*)d_in[3];
  const float* Wa = (const float*)d_in[4];
  const float* b  = (const float*)d_in[5];
  float* out = (float*)d_out;
  char* ws = (char*)d_ws;

  if (ws_size >= 204476416ull) {
    // ---- Tier 3: persistent step loop (L3-mediated coherence) ----
    unsigned short* WxT   = (unsigned short*)(ws);              //   8,388,608
    unsigned short* PW    = (unsigned short*)(ws + 8388608);    //  16,777,216
    unsigned short* xb2   = (unsigned short*)(ws + 25165824);   //  33,554,432
    unsigned short* Ab    = (unsigned short*)(ws + 58720256);   //   8,388,608
    unsigned short* xprojP= (unsigned short*)(ws + 67108864);   // 134,217,728
    unsigned short* hxA   = (unsigned short*)(ws + 201326592);  //   1,048,576
    unsigned short* hxB   = (unsigned short*)(ws + 202375168);  //   1,048,576
    float* cst            = (float*)(ws + 203423744);           //   1,048,576
    int* bars             = (int*)(ws + 204472320);             //       2,048

    hipFuncSetAttribute((const void*)k_steps,
                        hipFuncAttributeMaxDynamicSharedMemorySize, 86016);

    k_tw3<<<dim3(64, 16, 3), 256, 0, stream>>>(Wx, Wh, Wa, WxT, PW);
    k_conv_x2<<<4096, 256, 0, stream>>>(x, xb2);
    k_conv<<<1024, 256, 0, stream>>>(A, Ab, 1048576);
    k_init2<<<1024, 256, 0, stream>>>(A, hxA, cst);
    k_gemm_t<1><<<dim3(128, 32), 512, 0, stream>>>(xb2, WxT, xprojP);
    hipMemsetAsync(bars, 0, 2048, stream);
    k_steps<<<256, 512, 86016, stream>>>(Ab, PW, xprojP, b, hxA, hxB, cst, out, bars);
  } else if (ws_size >= 61341696ull) {
    // ---- Tier 0 fallback ----
    unsigned short* WT  = (unsigned short*)(ws);
    unsigned short* xb  = (unsigned short*)(ws + 25165824);
    unsigned short* hA  = (unsigned short*)(ws + 58720256);
    unsigned short* hB  = (unsigned short*)(ws + 59244544);
    unsigned short* atb = (unsigned short*)(ws + 59768832);
    float* cst          = (float*)(ws + 60293120);

    k_prep_w<<<dim3(64, 48), 256, 0, stream>>>(Wx, Wh, Wa, WT);
    k_conv<<<2048, 256, 0, stream>>>(x, xb, 4194304);
    k_init1<<<1024, 256, 0, stream>>>(A, hA, cst);
    for (int t = 0; t < 64; ++t) {
      const unsigned short* hr = (t & 1) ? hB : hA;
      unsigned short* hwv      = (t & 1) ? hA : hB;
      k_attn<<<256, 256, 0, stream>>>(A, hr, atb);
      k_step<<<dim3(64, 4), 512, 0, stream>>>(xb, WT, b, hr, atb, hwv, cst, out, t);
    }
  }
}

// Round 9
// 1166.757 us; speedup vs baseline: 4.6538x; 1.1407x over previous
//
#include <hip/hip_runtime.h>
#include <cstdint>
#include <cstddef>

#define T_S 64

typedef __attribute__((ext_vector_type(4))) float f32x4;
typedef __attribute__((ext_vector_type(2))) float f32x2;
typedef __attribute__((ext_vector_type(8))) short bh8;

__device__ __forceinline__ unsigned short f2b(float f) {
  uint32_t x = __builtin_bit_cast(uint32_t, f);
  uint32_t r = (x + 0x7FFFu + ((x >> 16) & 1u)) >> 16;
  return (unsigned short)r;
}
__device__ __forceinline__ float b2f(unsigned short u) {
  uint32_t v = ((uint32_t)u) << 16;
  return __builtin_bit_cast(float, v);
}

__device__ __forceinline__ void st_u32_l3(void* p, unsigned v) {
  asm volatile("global_store_dword %0, %1, off sc0 sc1" :: "v"(p), "v"(v) : "memory");
}

// store-based group barrier: block j stores epoch to slot j (parallel, no RMW
// serialization); lanes 0-63 poll the 32 slots (coalesced 128B sc0 sc1 load)
// until all >= target. All traffic at L3 coherence point; local L2 never
// invalidated. Safe: 86KB dyn LDS -> 1 blk/CU -> all 256 blocks co-resident.
__device__ __forceinline__ void gbar(int* slots, int jslot, int target) {
  __syncthreads();   // drains each wave's vmem (incl. sc0 sc1 stores)
  int tid = threadIdx.x;
  if (tid == 0)
    asm volatile("global_store_dword %0, %1, off sc0 sc1"
                 :: "v"(slots + jslot), "v"(target) : "memory");
  if (tid < 64) {
    const int* p = slots + (tid & 31);
    int v;
    do {
      __builtin_amdgcn_s_sleep(1);
      asm volatile("global_load_dword %0, %1, off sc0 sc1\n\ts_waitcnt vmcnt(0)"
                   : "=v"(v) : "v"(p) : "memory");
    } while (__any(v < target));
  }
  __syncthreads();
}

// ======================= prep =======================

__global__ void k_conv(const float* __restrict__ src, unsigned short* __restrict__ dst, int n4) {
  int i = blockIdx.x * blockDim.x + threadIdx.x;
  int stride = gridDim.x * blockDim.x;
  for (; i < n4; i += stride) {
    float4 v = ((const float4*)src)[i];
    ushort4 o; o.x = f2b(v.x); o.y = f2b(v.y); o.z = f2b(v.z); o.w = f2b(v.w);
    ((ushort4*)dst)[i] = o;
  }
}

// z=0 Wx -> WxT[4096][1024]; z=1/2 Wh/Wa -> PW[4096][2048] with row order
// prow = (hcol>>5)*128 + q*32 + (hcol&31)  for gate col = q*1024 + hcol.
__global__ __launch_bounds__(256) void k_tw3(
    const float* __restrict__ Wx, const float* __restrict__ Wh,
    const float* __restrict__ Wa,
    unsigned short* __restrict__ WxT, unsigned short* __restrict__ PW) {
  __shared__ float tile[64][65];
  int j0 = blockIdx.x * 64;
  int k0 = blockIdx.y * 64;
  int z = blockIdx.z;
  const float* src = (z == 0) ? Wx : (z == 1) ? Wh : Wa;
  for (int i = threadIdx.x; i < 4096; i += 256) {
    int r = i >> 6, c = i & 63;
    tile[r][c] = src[(size_t)(k0 + r) * 4096 + (j0 + c)];
  }
  __syncthreads();
  for (int i = threadIdx.x; i < 4096; i += 256) {
    int r = i >> 6, c = i & 63;
    int col = j0 + r;
    unsigned short v = f2b(tile[c][r]);
    if (z == 0) {
      WxT[(size_t)col * 1024 + (k0 + c)] = v;
    } else {
      int q = col >> 10, hcol = col & 1023;
      int prow = (hcol >> 5) * 128 + q * 32 + (hcol & 31);
      PW[(size_t)prow * 2048 + (size_t)(z - 1) * 1024 + (k0 + c)] = v;
    }
  }
}

// xb2[(t*256+n)][k] = bf16(x[n][t][k])
__global__ __launch_bounds__(256) void k_conv_x2(
    const float* __restrict__ x, unsigned short* __restrict__ xb2) {
  int b = blockIdx.x, tid = threadIdx.x;
  #pragma unroll
  for (int rr = 0; rr < 4; ++rr) {
    int r = b * 4 + rr;
    int t = r >> 8, n = r & 255;
    const float4* src = (const float4*)(x + ((size_t)n * 64 + t) * 1024);
    float4 v = src[tid];
    ushort4 o; o.x = f2b(v.x); o.y = f2b(v.y); o.z = f2b(v.z); o.w = f2b(v.w);
    ((ushort4*)(xb2 + (size_t)r * 1024))[tid] = o;
  }
}

// h0 = c0 = mean(A over 16); h -> hx[n][0..1024) row stride 2048
__global__ __launch_bounds__(256) void k_init2(
    const float* __restrict__ A, unsigned short* __restrict__ hx,
    float* __restrict__ cst) {
  int idx = blockIdx.x * 256 + threadIdx.x;
  const float4* a4 = (const float4*)(A + (size_t)idx * 16);
  float s = 0.f;
  #pragma unroll
  for (int q = 0; q < 4; ++q) { float4 v = a4[q]; s += v.x + v.y + v.z + v.w; }
  s *= 0.0625f;
  cst[idx] = s;
  hx[(size_t)(idx >> 10) * 2048 + (idx & 1023)] = f2b(s);
}

// Tier-0 h0 (row stride 1024)
__global__ __launch_bounds__(256) void k_init1(
    const float* __restrict__ A, unsigned short* __restrict__ hb,
    float* __restrict__ cst) {
  int idx = blockIdx.x * 256 + threadIdx.x;
  const float4* a4 = (const float4*)(A + (size_t)idx * 16);
  float s = 0.f;
  #pragma unroll
  for (int q = 0; q < 4; ++q) { float4 v = a4[q]; s += v.x + v.y + v.z + v.w; }
  s *= 0.0625f;
  cst[idx] = s;
  hb[idx] = f2b(s);
}

// C = A[M][1024] @ Bt[4096][1024]^T. PERM=1: xprojP layout
// off = row*4096 + (hcol>>5)*128 + q*32 + (hcol&31), col = q*1024 + hcol
template <int PERM>
__global__ __launch_bounds__(512) void k_gemm_t(
    const unsigned short* __restrict__ Asrc,
    const unsigned short* __restrict__ Bt,
    unsigned short* __restrict__ C) {
  __shared__ __align__(16) unsigned short smem[36864];
  int tid = threadIdx.x;
  int bx = blockIdx.x, by = blockIdx.y;
  int lane = tid & 63, wave = tid >> 6;
  int wr = wave >> 1, wc = wave & 1;
  int srow = tid >> 3;
  int scol = (tid & 7) * 8;
  const unsigned short* arow0 = Asrc + ((size_t)(bx * 128 + srow)) * 1024 + scol;
  const unsigned short* arow1 = arow0 + (size_t)64 * 1024;
  const unsigned short* brow0 = Bt + ((size_t)(by * 128 + srow)) * 1024 + scol;
  const unsigned short* brow1 = brow0 + (size_t)64 * 1024;

  f32x4 acc[2][4];
  #pragma unroll
  for (int m = 0; m < 2; ++m)
    #pragma unroll
    for (int nn = 0; nn < 4; ++nn) acc[m][nn] = {0.f, 0.f, 0.f, 0.f};

  uint4 ra0, ra1, rb0, rb1;
  auto gload = [&](int kt) {
    int k0 = kt * 64;
    ra0 = *(const uint4*)(arow0 + k0);
    ra1 = *(const uint4*)(arow1 + k0);
    rb0 = *(const uint4*)(brow0 + k0);
    rb1 = *(const uint4*)(brow1 + k0);
  };
  int frow = lane & 15, fk = (lane >> 4) * 8;
  gload(0);
  int cur = 0;
  for (int kt = 0; kt < 16; ++kt) {
    unsigned short* As = smem + cur * 18432;
    unsigned short* Bs = As + 9216;
    *(uint4*)(As + srow * 72 + scol) = ra0;
    *(uint4*)(As + (srow + 64) * 72 + scol) = ra1;
    *(uint4*)(Bs + srow * 72 + scol) = rb0;
    *(uint4*)(Bs + (srow + 64) * 72 + scol) = rb1;
    __syncthreads();
    if (kt + 1 < 16) gload(kt + 1);
    #pragma unroll
    for (int kk = 0; kk < 2; ++kk) {
      bh8 af[2], bf[4];
      #pragma unroll
      for (int m = 0; m < 2; ++m)
        af[m] = *(const bh8*)(As + (wr * 32 + m * 16 + frow) * 72 + kk * 32 + fk);
      #pragma unroll
      for (int nn = 0; nn < 4; ++nn)
        bf[nn] = *(const bh8*)(Bs + (wc * 64 + nn * 16 + frow) * 72 + kk * 32 + fk);
      #pragma unroll
      for (int m = 0; m < 2; ++m)
        #pragma unroll
        for (int nn = 0; nn < 4; ++nn)
          acc[m][nn] = __builtin_amdgcn_mfma_f32_16x16x32_bf16(af[m], bf[nn], acc[m][nn], 0, 0, 0);
    }
    cur ^= 1;
  }
  int rbase = bx * 128 + wr * 32 + (lane >> 4) * 4;
  int cbase = by * 128 + wc * 64 + frow;
  #pragma unroll
  for (int m = 0; m < 2; ++m)
    #pragma unroll
    for (int nn = 0; nn < 4; ++nn)
      #pragma unroll
      for (int reg = 0; reg < 4; ++reg) {
        size_t row = rbase + m * 16 + reg;
        int c = cbase + nn * 16;
        int q = c >> 10, hcol = c & 1023;
        size_t off = PERM ? ((size_t)row * 4096 + (hcol >> 5) * 128 + q * 32 + (hcol & 31))
                          : ((size_t)row * 4096 + c);
        C[off] = f2b(acc[m][nn][reg]);
      }
}

// ======================= persistent step loop =======================
// 256 blocks = 8 groups x 32. Group g owns rows [g*32,g*32+32). Block (g,j):
//   S+T: attention for row n = g*32+j  (hx via L3)
//   G:   32 rows x 128 gate-cols (j's slice), K=2048, depth-4 counted-vmcnt
//        pipeline, full-spread XOR LDS swizzle, raw s_barrier.
__global__ __launch_bounds__(512, 1) void k_steps(
    const unsigned short* __restrict__ Ab,     // [256][1024][16]
    const unsigned short* __restrict__ PW,     // [4096][2048], j*128+q*32+l major
    const unsigned short* __restrict__ xprojP, // [(t*256+n)][j*128+q*32+l]
    const float* __restrict__ bias,
    unsigned short* __restrict__ hxA,          // [256][2048] = [h|attn]
    unsigned short* __restrict__ hxB,
    const float* __restrict__ cst0,
    float* __restrict__ out,
    int* __restrict__ bars) {
  extern __shared__ __align__(16) char sm[];
  const int tid = threadIdx.x;
  const int bid = blockIdx.x;
  const int lane = tid & 63, wave = tid >> 6;
  const int wm = wave & 1, wc = wave >> 1;
  const int frow = lane & 15, fg = lane >> 4;
  const int g = bid >> 5, j = bid & 31;
  const int nbase = g * 32;
  const int nA = nbase + j;
  int* myslots = bars + (g << 6);   // 32 int slots per group, 256B-spaced

  const int erow = tid >> 4;          // 0..31
  const int el2 = (tid & 15) * 2;
  const int hcol = j * 32 + el2;

  // persistent per-thread state
  float creg[2];
  float brg[4][2];
  {
    const float* cp = cst0 + (size_t)(nbase + erow) * 1024 + hcol;
    creg[0] = cp[0]; creg[1] = cp[1];
    #pragma unroll
    for (int q = 0; q < 4; ++q) {
      brg[q][0] = bias[q * 1024 + hcol];
      brg[q][1] = bias[q * 1024 + hcol + 1];
    }
  }

  // staging global bases
  const int c16 = (tid & 15) * 16;
  const char* bB0 = (const char*)(PW + (size_t)(j * 128 + erow) * 2048) + c16;
  const char* bB1 = bB0 + 32 * 4096;
  const char* bB2 = bB0 + 64 * 4096;
  const char* bB3 = bB0 + 96 * 4096;
  const char* aBA = (const char*)(hxA + (size_t)(nbase + erow) * 2048) + c16;
  const char* aBB = (const char*)(hxB + (size_t)(nbase + erow) * 2048) + c16;

  // full-spread XOR swizzle (bits 4-7): row r's 16B slot c stored at c^((r&15)<<4).
  // Read side rows (frow, frow+16, wc*32+frow) all satisfy (row&15)==frow.
  const int wA = (erow * 256 + c16) ^ ((erow & 15) << 4);
  const int qA = ((wm * 16 + frow) * 256 + fg * 16) ^ ((frow & 15) << 4);
  const int qB = ((wc * 32 + frow) * 256 + fg * 16) ^ ((frow & 15) << 4);

  uint4 sa0, sa1, sa2, sa3;
  uint4 sb00, sb01, sb02, sb03;
  uint4 sb10, sb11, sb12, sb13;
  uint4 sb20, sb21, sb22, sb23;
  uint4 sb30, sb31, sb32, sb33;

#define LOADST(st, ktL) \
  asm volatile("global_load_dwordx4 %0, %1, off offset:%c2 sc0 sc1" : "=v"(sa##st) : "v"(aB), "i"((ktL) * 256)); \
  asm volatile("global_load_dwordx4 %0, %1, off offset:%c2" : "=v"(sb##st##0) : "v"(bB0), "i"((ktL) * 256)); \
  asm volatile("global_load_dwordx4 %0, %1, off offset:%c2" : "=v"(sb##st##1) : "v"(bB1), "i"((ktL) * 256)); \
  asm volatile("global_load_dwordx4 %0, %1, off offset:%c2" : "=v"(sb##st##2) : "v"(bB2), "i"((ktL) * 256)); \
  asm volatile("global_load_dwordx4 %0, %1, off offset:%c2" : "=v"(sb##st##3) : "v"(bB3), "i"((ktL) * 256));

#define GSTEP(kt, st, bufo, WN) { \
  asm volatile("s_waitcnt vmcnt(" #WN ")" ::: "memory"); \
  *(uint4*)(sm + (bufo) + wA) = sa##st; \
  *(uint4*)(sm + (bufo) + 8192 + wA) = sb##st##0; \
  *(uint4*)(sm + (bufo) + 8192 + wA + 8192) = sb##st##1; \
  *(uint4*)(sm + (bufo) + 8192 + wA + 16384) = sb##st##2; \
  *(uint4*)(sm + (bufo) + 8192 + wA + 24576) = sb##st##3; \
  if ((kt) + 4 < 16) { LOADST(st, (kt) + 4) } \
  asm volatile("s_waitcnt lgkmcnt(0)" ::: "memory"); \
  __builtin_amdgcn_s_barrier(); \
  _Pragma("unroll") \
  for (int kk = 0; kk < 4; ++kk) { \
    bh8 af  = *(const bh8*)(sm + (bufo) + (qA ^ (kk << 6))); \
    bh8 bf0 = *(const bh8*)(sm + (bufo) + 8192 + (qB ^ (kk << 6))); \
    bh8 bf1 = *(const bh8*)(sm + (bufo) + 8192 + 4096 + (qB ^ (kk << 6))); \
    acc0 = __builtin_amdgcn_mfma_f32_16x16x32_bf16(af, bf0, acc0, 0, 0, 0); \
    acc1 = __builtin_amdgcn_mfma_f32_16x16x32_bf16(af, bf1, acc1, 0, 0, 0); \
  } \
}

  int nb = 0;
  for (int t = 0; t < 64; ++t) {
    unsigned short* hxc = (t & 1) ? hxB : hxA;
    unsigned short* hxn = (t & 1) ? hxA : hxB;
    const char* aB = (t & 1) ? aBB : aBA;

    // ---------- Phase S+T: attention for n = nA ----------
    {
      unsigned hh;
      asm volatile("global_load_dword %0, %1, off sc0 sc1"
                   : "=v"(hh) : "v"(hxc + (size_t)nA * 2048 + tid * 2));
      const unsigned short* ap = Ab + (size_t)nA * 16384 + tid * 32;
      bh8 a0 = *(const bh8*)(ap);
      bh8 a1 = *(const bh8*)(ap + 8);
      bh8 a2 = *(const bh8*)(ap + 16);
      bh8 a3 = *(const bh8*)(ap + 24);
      asm volatile("s_waitcnt vmcnt(0)" ::: "memory");
      __builtin_amdgcn_sched_barrier(0);
      float hv0 = b2f((unsigned short)(hh & 0xffff));
      float hv1 = b2f((unsigned short)(hh >> 16));
      float s[16];
      #pragma unroll
      for (int p = 0; p < 8; ++p) {
        s[p]     = hv0 * b2f((unsigned short)a0[p]) + hv1 * b2f((unsigned short)a2[p]);
        s[8 + p] = hv0 * b2f((unsigned short)a1[p]) + hv1 * b2f((unsigned short)a3[p]);
      }
      #pragma unroll
      for (int p = 0; p < 16; ++p) {
        float v = s[p];
        #pragma unroll
        for (int off = 32; off > 0; off >>= 1) v += __shfl_xor(v, off);
        s[p] = v;
      }
      float* red = (float*)sm;     // [8][16]
      float* scs = red + 128;      // [16]
      if (lane == 0) {
        #pragma unroll
        for (int p = 0; p < 16; ++p) red[wave * 16 + p] = s[p];
      }
      __syncthreads();
      if (tid < 16) {
        float v = 0.f;
        #pragma unroll
        for (int wv = 0; wv < 8; ++wv) v += red[wv * 16 + tid];
        scs[tid] = v * 0.03125f;
      }
      __syncthreads();
      float sc[16];
      #pragma unroll
      for (int p = 0; p < 16; ++p) sc[p] = scs[p];
      float m = sc[0];
      #pragma unroll
      for (int p = 1; p < 16; ++p) m = fmaxf(m, sc[p]);
      float w[16]; float sum = 0.f;
      #pragma unroll
      for (int p = 0; p < 16; ++p) { w[p] = __expf(sc[p] - m); sum += w[p]; }
      float inv = 1.0f / sum;
      float at0 = 0.f, at1 = 0.f;
      #pragma unroll
      for (int p = 0; p < 8; ++p) {
        at0 += w[p] * b2f((unsigned short)a0[p]) + w[8 + p] * b2f((unsigned short)a1[p]);
        at1 += w[p] * b2f((unsigned short)a2[p]) + w[8 + p] * b2f((unsigned short)a3[p]);
      }
      at0 *= inv; at1 *= inv;
      unsigned packed = (unsigned)f2b(at0) | ((unsigned)f2b(at1) << 16);
      st_u32_l3(hxc + (size_t)nA * 2048 + 1024 + tid * 2, packed);
    }
    nb += 1; gbar(myslots, j, nb);

    // ---------- Phase G ----------
    {
      const unsigned short* xqp = xprojP + ((size_t)(t * 256 + nbase + erow)) * 4096
                                  + j * 128 + (tid & 15) * 8;
      uint4 xq;
      asm volatile("global_load_dwordx4 %0, %1, off nt" : "=v"(xq) : "v"(xqp));
      f32x4 acc0 = {0.f, 0.f, 0.f, 0.f};
      f32x4 acc1 = {0.f, 0.f, 0.f, 0.f};
      LOADST(0, 0) LOADST(1, 1) LOADST(2, 2) LOADST(3, 3)
      GSTEP(0, 0, 0, 15)      GSTEP(1, 1, 40960, 15)
      GSTEP(2, 2, 0, 15)      GSTEP(3, 3, 40960, 15)
      GSTEP(4, 0, 0, 15)      GSTEP(5, 1, 40960, 15)
      GSTEP(6, 2, 0, 15)      GSTEP(7, 3, 40960, 15)
      GSTEP(8, 0, 0, 15)      GSTEP(9, 1, 40960, 15)
      GSTEP(10, 2, 0, 15)     GSTEP(11, 3, 40960, 15)
      GSTEP(12, 0, 0, 15)     GSTEP(13, 1, 40960, 10)
      GSTEP(14, 2, 0, 5)      GSTEP(15, 3, 40960, 0)
      __syncthreads();
      float* a_lds = (float*)sm;                       // [32][132] f32
      unsigned short* xp = (unsigned short*)(sm + 16896); // [32][136] shorts
      {
        int r0 = wm * 16 + fg * 4;
        int c0 = wc * 32 + frow;
        #pragma unroll
        for (int r = 0; r < 4; ++r) {
          a_lds[(r0 + r) * 132 + c0]      = acc0[r];
          a_lds[(r0 + r) * 132 + c0 + 16] = acc1[r];
        }
        *(uint4*)(xp + erow * 136 + (tid & 15) * 8) = xq;
      }
      __syncthreads();
      {
        float h2[2];
        #pragma unroll
        for (int e = 0; e < 2; ++e) {
          float pre[4];
          #pragma unroll
          for (int q = 0; q < 4; ++q)
            pre[q] = a_lds[erow * 132 + q * 32 + el2 + e]
                   + b2f(xp[erow * 136 + q * 32 + el2 + e]) + brg[q][e];
          float si = 1.0f / (1.0f + __expf(-pre[0]));
          float sf = 1.0f / (1.0f + __expf(-pre[1]));
          float so = 1.0f / (1.0f + __expf(-pre[2]));
          float tg = 2.0f / (1.0f + __expf(-2.0f * pre[3])) - 1.0f;
          float cn = sf * creg[e] + si * tg;
          creg[e] = cn;
          h2[e] = so * (2.0f / (1.0f + __expf(-2.0f * cn)) - 1.0f);
        }
        f32x2 o2 = {h2[0], h2[1]};
        __builtin_nontemporal_store(o2,
            (f32x2*)(out + ((size_t)(nbase + erow) * T_S + t) * 1024 + hcol));
        unsigned hp = (unsigned)f2b(h2[0]) | ((unsigned)f2b(h2[1]) << 16);
        st_u32_l3(hxn + (size_t)(nbase + erow) * 2048 + hcol, hp);
      }
    }
    nb += 1; gbar(myslots, j, nb);
  }
#undef GSTEP
#undef LOADST
}

// ======================= TIER 0 fallback =======================

__global__ __launch_bounds__(256) void k_prep_w(
    const float* __restrict__ Wx, const float* __restrict__ Wh,
    const float* __restrict__ Wa, unsigned short* __restrict__ WT) {
  __shared__ float tile[64][65];
  int j0 = blockIdx.x * 64;
  int k0 = blockIdx.y * 64;
  const float* src; int kk0;
  if (k0 < 1024)      { src = Wx; kk0 = k0; }
  else if (k0 < 2048) { src = Wh; kk0 = k0 - 1024; }
  else                { src = Wa; kk0 = k0 - 2048; }
  for (int i = threadIdx.x; i < 4096; i += 256) {
    int r = i >> 6, c = i & 63;
    tile[r][c] = src[(size_t)(kk0 + r) * 4096 + (j0 + c)];
  }
  __syncthreads();
  for (int i = threadIdx.x; i < 4096; i += 256) {
    int r = i >> 6, c = i & 63;
    WT[(size_t)(j0 + r) * 3072 + (k0 + c)] = f2b(tile[c][r]);
  }
}

__global__ __launch_bounds__(256) void k_attn(
    const float* __restrict__ A, const unsigned short* __restrict__ hb,
    unsigned short* __restrict__ attnb) {
  int n = blockIdx.x;
  int tid = threadIdx.x;
  int lane = tid & 63, wave = tid >> 6;
  float areg[4][16];
  float s[16];
  #pragma unroll
  for (int p = 0; p < 16; ++p) s[p] = 0.f;
  #pragma unroll
  for (int r = 0; r < 4; ++r) {
    int h = r * 256 + tid;
    size_t base = (size_t)n * 1024 + h;
    const float4* a4 = (const float4*)(A + base * 16);
    #pragma unroll
    for (int q = 0; q < 4; ++q) {
      float4 v = a4[q];
      areg[r][q*4+0] = v.x; areg[r][q*4+1] = v.y;
      areg[r][q*4+2] = v.z; areg[r][q*4+3] = v.w;
    }
    float hv = b2f(hb[base]);
    #pragma unroll
    for (int p = 0; p < 16; ++p) s[p] += hv * areg[r][p];
  }
  #pragma unroll
  for (int p = 0; p < 16; ++p) {
    float v = s[p];
    #pragma unroll
    for (int off = 32; off > 0; off >>= 1) v += __shfl_xor(v, off);
    s[p] = v;
  }
  __shared__ float red[4][16];
  __shared__ float sc_sh[16];
  if (lane == 0) {
    #pragma unroll
    for (int p = 0; p < 16; ++p) red[wave][p] = s[p];
  }
  __syncthreads();
  if (tid < 16) {
    sc_sh[tid] = (red[0][tid] + red[1][tid] + red[2][tid] + red[3][tid]) * 0.03125f;
  }
  __syncthreads();
  float sc[16];
  #pragma unroll
  for (int p = 0; p < 16; ++p) sc[p] = sc_sh[p];
  float m = sc[0];
  #pragma unroll
  for (int p = 1; p < 16; ++p) m = fmaxf(m, sc[p]);
  float e[16]; float sum = 0.f;
  #pragma unroll
  for (int p = 0; p < 16; ++p) { e[p] = __expf(sc[p] - m); sum += e[p]; }
  float inv = 1.0f / sum;
  #pragma unroll
  for (int r = 0; r < 4; ++r) {
    float a = 0.f;
    #pragma unroll
    for (int p = 0; p < 16; ++p) a += areg[r][p] * e[p];
    attnb[(size_t)n * 1024 + r * 256 + tid] = f2b(a * inv);
  }
}

__global__ __launch_bounds__(512) void k_step(
    const unsigned short* __restrict__ xb,
    const unsigned short* __restrict__ WT,
    const float* __restrict__ bias,
    const unsigned short* __restrict__ hr,
    const unsigned short* __restrict__ atb,
    unsigned short* __restrict__ hw,
    float* __restrict__ cst,
    float* __restrict__ out,
    int t)
{
  __shared__ __align__(16) unsigned short smem[18432];
  int tid = threadIdx.x;
  int bn = blockIdx.x;
  int bm = blockIdx.y;
  int lane = tid & 63;
  int wave = tid >> 6;
  int wr = wave >> 1;
  int wc = wave & 1;
  int nbase = bm * 64;
  int j0 = bn * 16;
  int srow = tid >> 3;
  int scol = (tid & 7) * 8;
  int bj = ((srow >> 4) * 1024) + j0 + (srow & 15);
  const unsigned short* bsrc = WT + (size_t)bj * 3072 + scol;
  f32x4 acc0 = {0.f, 0.f, 0.f, 0.f};
  f32x4 acc1 = {0.f, 0.f, 0.f, 0.f};
  uint4 ra, rb;
  auto gload = [&](int kt) {
    int k0 = kt * 64;
    const unsigned short* src; size_t rs; int kloc;
    if (k0 < 1024)      { src = xb + (size_t)t * 1024; rs = (size_t)T_S * 1024; kloc = k0; }
    else if (k0 < 2048) { src = hr;  rs = 1024; kloc = k0 - 1024; }
    else                { src = atb; rs = 1024; kloc = k0 - 2048; }
    ra = *(const uint4*)(src + (size_t)(nbase + srow) * rs + kloc + scol);
    rb = *(const uint4*)(bsrc + k0);
  };
  int frow = lane & 15;
  int fk = (lane >> 4) * 8;
  gload(0);
  int cur = 0;
  for (int kt = 0; kt < 48; ++kt) {
    unsigned short* As = smem + cur * 4608;
    unsigned short* Bs = smem + 9216 + cur * 4608;
    *(uint4*)(As + srow * 72 + scol) = ra;
    *(uint4*)(Bs + srow * 72 + scol) = rb;
    __syncthreads();
    if (kt + 1 < 48) gload(kt + 1);
    #pragma unroll
    for (int kk = 0; kk < 2; ++kk) {
      bh8 af  = *(const bh8*)(As + (wr * 16 + frow) * 72 + kk * 32 + fk);
      bh8 bf0 = *(const bh8*)(Bs + (wc * 32 + frow) * 72 + kk * 32 + fk);
      bh8 bf1 = *(const bh8*)(Bs + (wc * 32 + 16 + frow) * 72 + kk * 32 + fk);
      acc0 = __builtin_amdgcn_mfma_f32_16x16x32_bf16(af, bf0, acc0, 0, 0, 0);
      acc1 = __builtin_amdgcn_mfma_f32_16x16x32_bf16(af, bf1, acc1, 0, 0, 0);
    }
    cur ^= 1;
  }
  __syncthreads();
  float* a_lds = (float*)smem;
  {
    int r0 = wr * 16 + (lane >> 4) * 4;
    int c0 = wc * 32 + frow;
    #pragma unroll
    for (int reg = 0; reg < 4; ++reg) {
      a_lds[(r0 + reg) * 65 + c0]      = acc0[reg];
      a_lds[(r0 + reg) * 65 + c0 + 16] = acc1[reg];
    }
  }
  __syncthreads();
  #pragma unroll
  for (int r = 0; r < 2; ++r) {
    int pi = r * 512 + tid;
    int row = pi >> 4, gl = pi & 15;
    int n = nbase + row;
    int gcol = j0 + gl;
    float ii = a_lds[row * 65 + gl]      + bias[gcol];
    float ff = a_lds[row * 65 + 16 + gl] + bias[1024 + gcol];
    float oo = a_lds[row * 65 + 32 + gl] + bias[2048 + gcol];
    float gg = a_lds[row * 65 + 48 + gl] + bias[3072 + gcol];
    size_t ci = (size_t)n * 1024 + gcol;
    float cold = cst[ci];
    float si = 1.0f / (1.0f + __expf(-ii));
    float sf = 1.0f / (1.0f + __expf(-ff));
    float so = 1.0f / (1.0f + __expf(-oo));
    float tg = 2.0f / (1.0f + __expf(-2.0f * gg)) - 1.0f;
    float cn = sf * cold + si * tg;
    float hn = so * (2.0f / (1.0f + __expf(-2.0f * cn)) - 1.0f);
    cst[ci] = cn;
    out[((size_t)n * T_S + t) * 1024 + gcol] = hn;
    hw[ci] = f2b(hn);
  }
}

// ======================= host =======================

extern "C" void kernel_launch(void* const* d_in, const int* in_sizes, int n_in,
                              void* d_out, int out_size, void* d_ws, size_t ws_size,
                              hipStream_t stream) {
  const float* x  = (const float*)d_in[0];
  const float* A  = (const float*)d_in[1];
  const float* Wx = (const float*)d_in[2];
  const float* Wh = (const float*)d_in[3];
  const float* Wa = (const float*)d_in[4];
  const float* b  = (const float*)d_in[5];
  float* out = (float*)d_out;
  char* ws = (char*)d_ws;

  if (ws_size >= 204476416ull) {
    // ---- Tier 3: persistent step loop (L3-mediated coherence) ----
    unsigned short* WxT   = (unsigned short*)(ws);              //   8,388,608
    unsigned short* PW    = (unsigned short*)(ws + 8388608);    //  16,777,216
    unsigned short* xb2   = (unsigned short*)(ws + 25165824);   //  33,554,432
    unsigned short* Ab    = (unsigned short*)(ws + 58720256);   //   8,388,608
    unsigned short* xprojP= (unsigned short*)(ws + 67108864);   // 134,217,728
    unsigned short* hxA   = (unsigned short*)(ws + 201326592);  //   1,048,576
    unsigned short* hxB   = (unsigned short*)(ws + 202375168);  //   1,048,576
    float* cst            = (float*)(ws + 203423744);           //   1,048,576
    int* bars             = (int*)(ws + 204472320);             //       2,048

    hipFuncSetAttribute((const void*)k_steps,
                        hipFuncAttributeMaxDynamicSharedMemorySize, 86016);

    k_tw3<<<dim3(64, 16, 3), 256, 0, stream>>>(Wx, Wh, Wa, WxT, PW);
    k_conv_x2<<<4096, 256, 0, stream>>>(x, xb2);
    k_conv<<<1024, 256, 0, stream>>>(A, Ab, 1048576);
    k_init2<<<1024, 256, 0, stream>>>(A, hxA, cst);
    k_gemm_t<1><<<dim3(128, 32), 512, 0, stream>>>(xb2, WxT, xprojP);
    hipMemsetAsync(bars, 0, 2048, stream);
    k_steps<<<256, 512, 86016, stream>>>(Ab, PW, xprojP, b, hxA, hxB, cst, out, bars);
  } else if (ws_size >= 61341696ull) {
    // ---- Tier 0 fallback ----
    unsigned short* WT  = (unsigned short*)(ws);
    unsigned short* xb  = (unsigned short*)(ws + 25165824);
    unsigned short* hA  = (unsigned short*)(ws + 58720256);
    unsigned short* hB  = (unsigned short*)(ws + 59244544);
    unsigned short* atb = (unsigned short*)(ws + 59768832);
    float* cst          = (float*)(ws + 60293120);

    k_prep_w<<<dim3(64, 48), 256, 0, stream>>>(Wx, Wh, Wa, WT);
    k_conv<<<2048, 256, 0, stream>>>(x, xb, 4194304);
    k_init1<<<1024, 256, 0, stream>>>(A, hA, cst);
    for (int t = 0; t < 64; ++t) {
      const unsigned short* hr = (t & 1) ? hB : hA;
      unsigned short* hwv      = (t & 1) ? hA : hB;
      k_attn<<<256, 256, 0, stream>>>(A, hr, atb);
      k_step<<<dim3(64, 4), 512, 0, stream>>>(xb, WT, b, hr, atb, hwv, cst, out, t);
    }
  }
}